// Round 8
// baseline (2478.537 us; speedup 1.0000x reference)
//
#include <hip/hip_runtime.h>
#include <math.h>

// MySimpleRNN on MI355X — BR=16 streaming, wx LDS/reg-resident, wh kb0-1
// reg-resident, conflict-free x staging.
// h = tanh(x_t@wx + b + h@wh), 64 steps, B=4096, NF=128, NH=512.
//
// Settled facts: weight stream is PER-CU limited (~64 B/clk L1 fill; R6);
// VGPR residency is safe only well under the 128-reg cap (R4/R5 spilled at
// 320 over-cap; R7 ran 56 regs clean). R7 = 11.9 us/step: MFMA 3.9, stream
// 1.14 MB = 7.4 (recurrence phase only), x-proj/epilogue/barriers ~3-4 with
// the port idle, ~0.4 conflicts (x-stage scatter).
// This round: (1) 17 loop-invariant frags (9 wx + 8 wh kb0,1) as NAMED
// pre-loop SSA consts (68 VGPR, total ~110 < 128; worst case remat = R7).
// Stream 1.14 -> 0.875 MB/step. (2) kb2 early-prefetch overlaps x-proj.
// (3) x staged by 256 threads as full 16B lane-frags -> zero LDS conflicts.
// Numerics: identical product set + accumulation order as R2/R7.
//
// mfma_f32_16x16x32_f16 layouts (verified learn_hip m89/m91/m120):
//   A: lane holds A[m=lane&15][k=(lane>>4)*8+j], j=0..7
//   B: lane holds B[k=(lane>>4)*8+j][n=lane&15]
//   C/D: reg r holds C[row=(lane>>4)*4+r][col=lane&15]

#define T_STEPS 64
#define NFD     128
#define NHD     512
#define BR      16
#define THREADS 1024         // 16 waves, 4 per SIMD

typedef _Float16 half8 __attribute__((ext_vector_type(8)));
typedef float float4v __attribute__((ext_vector_type(4)));

// ---- prep: split wh/wx into fp16 hi/lo, pack B-fragment-linear (round-2 layout, proven) ----
__global__ __launch_bounds__(256) void rnn_prep(
    const float* __restrict__ wh, const float* __restrict__ wx,
    _Float16* __restrict__ whp_hi, _Float16* __restrict__ whp_lo,
    _Float16* __restrict__ wxp_hi, _Float16* __restrict__ wxp_lo)
{
    int idx = blockIdx.x * 256 + threadIdx.x;   // 0..262143
    {
        int j  = idx & 7;
        int l  = (idx >> 3) & 63;
        int nt = (idx >> 9) & 3;
        int kb = (idx >> 11) & 15;
        int w  = idx >> 15;                     // 0..7
        int k  = kb * 32 + (l >> 4) * 8 + j;
        int n  = w * 64 + nt * 16 + (l & 15);
        float v = wh[k * NHD + n];
        _Float16 hi = (_Float16)v;
        whp_hi[idx] = hi;
        whp_lo[idx] = (_Float16)(v - (float)hi);
    }
    if (idx < 65536) {
        int j  = idx & 7;
        int l  = (idx >> 3) & 63;
        int nt = (idx >> 9) & 3;
        int kb = (idx >> 11) & 3;
        int w  = idx >> 13;                     // 0..7
        int k  = kb * 32 + (l >> 4) * 8 + j;
        int n  = w * 64 + nt * 16 + (l & 15);
        float v = wx[k * NHD + n];
        _Float16 hi = (_Float16)v;
        wxp_hi[idx] = hi;
        wxp_lo[idx] = (_Float16)(v - (float)hi);
    }
}

// branch-free tanh: clamp +-9, (e-1)/(e+1), e = 2^(2x*log2e)
__device__ __forceinline__ float fast_tanh(float v) {
    float xc = fminf(fmaxf(v, -9.0f), 9.0f);
    float e  = __builtin_amdgcn_exp2f(xc * 2.8853900817779268f);
    return (e - 1.0f) * __builtin_amdgcn_rcpf(e + 1.0f);
}

#define MFMA6(AH, AL, BH0, BH1, BL0, BL1)                                          \
    acc[0] = __builtin_amdgcn_mfma_f32_16x16x32_f16((AH), (BH0), acc[0], 0, 0, 0); \
    acc[0] = __builtin_amdgcn_mfma_f32_16x16x32_f16((AL), (BH0), acc[0], 0, 0, 0); \
    acc[0] = __builtin_amdgcn_mfma_f32_16x16x32_f16((AH), (BL0), acc[0], 0, 0, 0); \
    acc[1] = __builtin_amdgcn_mfma_f32_16x16x32_f16((AH), (BH1), acc[1], 0, 0, 0); \
    acc[1] = __builtin_amdgcn_mfma_f32_16x16x32_f16((AL), (BH1), acc[1], 0, 0, 0); \
    acc[1] = __builtin_amdgcn_mfma_f32_16x16x32_f16((AH), (BL1), acc[1], 0, 0, 0);

// ---- main fused recurrence ----
__global__ __launch_bounds__(THREADS, 4) void rnn_mfma(
    const float* __restrict__ x,
    const float* __restrict__ bias,
    const _Float16* __restrict__ whp_hi, const _Float16* __restrict__ whp_lo,
    const _Float16* __restrict__ wxp_hi, const _Float16* __restrict__ wxp_lo,
    float* __restrict__ out)
{
    // fragment-linear LDS: [kb][lane][j] halfs, 16B/lane contiguous per kb.
    __shared__ _Float16 s_fh[16 * 64 * 8];     // h hi, 16 KB
    __shared__ _Float16 s_fl[16 * 64 * 8];     // h lo, 16 KB
    __shared__ _Float16 s_xh[4 * 64 * 8];      // x hi,  4 KB
    __shared__ _Float16 s_xl[4 * 64 * 8];      // x lo,  4 KB
    // LDS-resident wx_hi frags: [wave][f(7)][lane][8], f = kb*2+nt (f<7) -> 112 KB
    __shared__ _Float16 s_w[16 * 7 * 64 * 8];  // total 152 KB

    const int tid  = (int)threadIdx.x;
    const int lane = tid & 63;
    const int w    = tid >> 6;        // wave 0..15, owns cols [w*32, w*32+32)
    const int m    = lane & 15;
    const int quad = lane >> 4;
    const int row0 = (int)blockIdx.x * BR;

    // zero h fragments (h(0) = 0)
    for (int i = tid; i < 16 * 64 * 8; i += THREADS) {
        s_fh[i] = (_Float16)0.f;
        s_fl[i] = (_Float16)0.f;
    }

    // bias for this lane's 2 col-tiles
    float bv[2];
    #pragma unroll
    for (int nt = 0; nt < 2; ++nt) bv[nt] = bias[w * 32 + nt * 16 + m];

    // weight fragment base pointers (round-2 math: 32-col slice of 64-col group)
    const half8* wxh = (const half8*)wxp_hi + (size_t)(w >> 1) * 1024 + (w & 1) * 128;
    const half8* wxl = (const half8*)wxp_lo + (size_t)(w >> 1) * 1024 + (w & 1) * 128;
    const half8* whh = (const half8*)whp_hi + (size_t)(w >> 1) * 4096 + (w & 1) * 128;
    const half8* whl = (const half8*)whp_lo + (size_t)(w >> 1) * 4096 + (w & 1) * 128;

    // stage resident wx_hi frags (f = kb*2+nt, f<7) into LDS once
    #pragma unroll
    for (int f = 0; f < 7; ++f) {
        int kb = f >> 1, nt = f & 1;
        half8 v = wxh[kb * 256 + nt * 64 + lane];
        *(half8*)&s_w[((w * 7 + f) * 64 + lane) * 8] = v;
    }

    // ---- loop-invariant register-resident frags (named SSA, 17 frags = 68 VGPR) ----
    // wx leftovers: hi kb3 nt1 + all 8 lo
    const half8 XH31 = wxh[3 * 256 + 64 + lane];
    const half8 XL00 = wxl[0 * 256 + lane],      XL01 = wxl[0 * 256 + 64 + lane];
    const half8 XL10 = wxl[1 * 256 + lane],      XL11 = wxl[1 * 256 + 64 + lane];
    const half8 XL20 = wxl[2 * 256 + lane],      XL21 = wxl[2 * 256 + 64 + lane];
    const half8 XL30 = wxl[3 * 256 + lane],      XL31 = wxl[3 * 256 + 64 + lane];
    // wh kb0, kb1 (hi+lo, nt0+nt1)
    const half8 WH0h0 = whh[0 * 256 + lane],     WH0h1 = whh[0 * 256 + 64 + lane];
    const half8 WH0l0 = whl[0 * 256 + lane],     WH0l1 = whl[0 * 256 + 64 + lane];
    const half8 WH1h0 = whh[1 * 256 + lane],     WH1h1 = whh[1 * 256 + 64 + lane];
    const half8 WH1l0 = whl[1 * 256 + lane],     WH1l1 = whl[1 * 256 + 64 + lane];

    // x staging: 256 threads each own one full A-fragment lane-slice (16B):
    // frag (xkb = i>>6, lane' = i&63) holds x[row0 + (lane'&15)][xkb*32 + (lane'>>4)*8 + j]
    const int xi    = tid & 255;
    const int xkb   = xi >> 6;
    const int xlane = xi & 63;
    const float* xptr = x + (size_t)(row0 + (xlane & 15)) * (T_STEPS * NFD)
                          + xkb * 32 + (xlane >> 4) * 8;
    float4v pxa, pxb;
    if (tid < 256) {
        pxa = *(const float4v*)xptr;
        pxb = *(const float4v*)(xptr + 4);
    }

    // epilogue fragment coords (R4/R5/R7, proven)
    const int eBase = w * 64 * 8 + (m & 7);
    const int eQ    = quad * 4;
    const int eHiM  = 16 * (m >> 3);

    for (int t = 0; t < T_STEPS; ++t) {
        // (a) stage x(t): fp32 -> hi/lo fp16, one 16B lane-frag per thread
        //     (linear across the wave -> zero bank conflicts)
        if (tid < 256) {
            half8 vh, vl;
            float xs[8] = {pxa[0], pxa[1], pxa[2], pxa[3],
                           pxb[0], pxb[1], pxb[2], pxb[3]};
            #pragma unroll
            for (int j = 0; j < 8; ++j) {
                _Float16 hi = (_Float16)xs[j];
                vh[j] = hi;
                vl[j] = (_Float16)(xs[j] - (float)hi);
            }
            *(half8*)&s_xh[xi * 8] = vh;
            *(half8*)&s_xl[xi * 8] = vl;
        }
        __syncthreads();   // (1) x staged + h(t-1) frags (+ t=0: s_w, zeros) visible

        if (t + 1 < T_STEPS && tid < 256) {
            pxa = *(const float4v*)(xptr + (t + 1) * NFD);
            pxb = *(const float4v*)(xptr + (t + 1) * NFD + 4);
        }

        // early prefetch of first streamed wh k-block (kb2): overlaps x-proj
        half8 P2h0 = whh[2 * 256 + lane],      P2h1 = whh[2 * 256 + 64 + lane];
        half8 P2l0 = whl[2 * 256 + lane],      P2l1 = whl[2 * 256 + 64 + lane];

        float4v acc[2];
        #pragma unroll
        for (int nt = 0; nt < 2; ++nt) {
            acc[nt][0] = bv[nt]; acc[nt][1] = bv[nt];
            acc[nt][2] = bv[nt]; acc[nt][3] = bv[nt];
        }

        // (b) input projection: K = 128 -> 4 k-blocks; all operands LDS/regs
        {
            half8 ah, al;
            ah = *(const half8*)&s_xh[(0 * 64 + lane) * 8];
            al = *(const half8*)&s_xl[(0 * 64 + lane) * 8];
            MFMA6(ah, al,
                  *(const half8*)&s_w[((w * 7 + 0) * 64 + lane) * 8],
                  *(const half8*)&s_w[((w * 7 + 1) * 64 + lane) * 8], XL00, XL01);
            ah = *(const half8*)&s_xh[(1 * 64 + lane) * 8];
            al = *(const half8*)&s_xl[(1 * 64 + lane) * 8];
            MFMA6(ah, al,
                  *(const half8*)&s_w[((w * 7 + 2) * 64 + lane) * 8],
                  *(const half8*)&s_w[((w * 7 + 3) * 64 + lane) * 8], XL10, XL11);
            ah = *(const half8*)&s_xh[(2 * 64 + lane) * 8];
            al = *(const half8*)&s_xl[(2 * 64 + lane) * 8];
            MFMA6(ah, al,
                  *(const half8*)&s_w[((w * 7 + 4) * 64 + lane) * 8],
                  *(const half8*)&s_w[((w * 7 + 5) * 64 + lane) * 8], XL20, XL21);
            ah = *(const half8*)&s_xh[(3 * 64 + lane) * 8];
            al = *(const half8*)&s_xl[(3 * 64 + lane) * 8];
            MFMA6(ah, al,
                  *(const half8*)&s_w[((w * 7 + 6) * 64 + lane) * 8],
                  XH31, XL30, XL31);
        }

        // (c) recurrence: kb0,1 resident; kb2 prefetched; kb3..15 streamed
        {
            half8 ah, al;
            ah = *(const half8*)&s_fh[(0 * 64 + lane) * 8];
            al = *(const half8*)&s_fl[(0 * 64 + lane) * 8];
            MFMA6(ah, al, WH0h0, WH0h1, WH0l0, WH0l1);
            ah = *(const half8*)&s_fh[(1 * 64 + lane) * 8];
            al = *(const half8*)&s_fl[(1 * 64 + lane) * 8];
            MFMA6(ah, al, WH1h0, WH1h1, WH1l0, WH1l1);
            ah = *(const half8*)&s_fh[(2 * 64 + lane) * 8];
            al = *(const half8*)&s_fl[(2 * 64 + lane) * 8];
            MFMA6(ah, al, P2h0, P2h1, P2l0, P2l1);
        }
        #pragma unroll 4
        for (int kb = 3; kb < 16; ++kb) {
            half8 ah  = *(const half8*)&s_fh[(kb * 64 + lane) * 8];
            half8 al  = *(const half8*)&s_fl[(kb * 64 + lane) * 8];
            half8 bh0 = whh[kb * 256 + lane];
            half8 bh1 = whh[kb * 256 + 64 + lane];
            half8 bl0 = whl[kb * 256 + lane];
            half8 bl1 = whl[kb * 256 + 64 + lane];
            MFMA6(ah, al, bh0, bh1, bl0, bl1);
        }

        __syncthreads();   // (2) all h/x fragment reads for step t done

        // (d) epilogue: tanh, split, write h(t) fragments (or final output)
        if (t == T_STEPS - 1) {
            #pragma unroll
            for (int nt = 0; nt < 2; ++nt)
                #pragma unroll
                for (int r = 0; r < 4; ++r)
                    out[(size_t)(row0 + quad * 4 + r) * NHD + w * 32 + nt * 16 + m] =
                        fast_tanh(acc[nt][r]);
        } else {
            #pragma unroll
            for (int nt = 0; nt < 2; ++nt) {
                #pragma unroll
                for (int r = 0; r < 4; ++r) {
                    float v = fast_tanh(acc[nt][r]);
                    _Float16 hi = (_Float16)v;
                    int fo = eBase + (eQ + r + 16 * (nt * 2) + eHiM) * 8;
                    s_fh[fo] = hi;
                    s_fl[fo] = (_Float16)(v - (float)hi);
                }
            }
        }
    }
}

extern "C" void kernel_launch(void* const* d_in, const int* in_sizes, int n_in,
                              void* d_out, int out_size, void* d_ws, size_t ws_size,
                              hipStream_t stream) {
    const float* x    = (const float*)d_in[0];  // [B, 64, 128]
    const float* wx   = (const float*)d_in[1];  // [128, 512]
    const float* wh   = (const float*)d_in[2];  // [512, 512]
    const float* bias = (const float*)d_in[3];  // [512]
    float* out = (float*)d_out;                 // [B, 512]

    // workspace (fp16): whp_hi 512KB | whp_lo 512KB | wxp_hi 128KB | wxp_lo 128KB
    char* ws = (char*)d_ws;
    _Float16* whp_hi = (_Float16*)(ws);
    _Float16* whp_lo = (_Float16*)(ws + 524288);
    _Float16* wxp_hi = (_Float16*)(ws + 1048576);
    _Float16* wxp_lo = (_Float16*)(ws + 1048576 + 131072);

    rnn_prep<<<1024, 256, 0, stream>>>(wh, wx, whp_hi, whp_lo, wxp_hi, wxp_lo);

    const int B = in_sizes[0] / (T_STEPS * NFD);   // 4096
    rnn_mfma<<<B / BR, THREADS, 0, stream>>>(x, bias, whp_hi, whp_lo, wxp_hi, wxp_lo, out);
}

// Round 9
// 2438.847 us; speedup vs baseline: 1.0163x; 1.0163x over previous
//
#include <hip/hip_runtime.h>
#include <math.h>

// MySimpleRNN on MI355X — R7 base + software-pipelined weight stream.
// h = tanh(x_t@wx + b + h@wh), 64 steps, B=4096, NF=128, NH=512.
//
// Settled behavioral facts (R4/R5/R8): loop-invariant VGPR residency always
// spills (allocator targets 64 regs; values live across back-edge+barriers go
// to scratch). Only within-iteration transients crossing <=1 barrier survive
// (R7: 56 VGPR clean). R7 = 11.9 us/step: stream 1.14 MB at ~112 GB/s/CU
// confined to the recurrence phase; x-proj/epilogue/barriers leave the
// L2->CU port idle ~3 us/step.
// This round (overlap only, bytes unchanged):
//  1) 3-slot software pipeline over kb0..15: prologue issues kb0,kb1 before
//     x-proj; each iter issues kb+2 before consuming kb (2-deep in flight,
//     ~48 transient VGPRs, static indices via full unroll).
//  2) wx-leftover 9-frag prefetch at loop top (crosses barrier1; R7-proven).
//  3) conflict-free x staging (R8: 256 threads, one 16B A-frag each;
//     halved SQ_LDS_BANK_CONFLICT).
// Numerics: identical product set + accumulation order as R2/R7.
//
// mfma_f32_16x16x32_f16 layouts (verified learn_hip m89/m91/m120):
//   A: lane holds A[m=lane&15][k=(lane>>4)*8+j], j=0..7
//   B: lane holds B[k=(lane>>4)*8+j][n=lane&15]
//   C/D: reg r holds C[row=(lane>>4)*4+r][col=lane&15]

#define T_STEPS 64
#define NFD     128
#define NHD     512
#define BR      16
#define THREADS 1024         // 16 waves, 4 per SIMD

typedef _Float16 half8 __attribute__((ext_vector_type(8)));
typedef float float4v __attribute__((ext_vector_type(4)));

// ---- prep: split wh/wx into fp16 hi/lo, pack B-fragment-linear (round-2 layout, proven) ----
__global__ __launch_bounds__(256) void rnn_prep(
    const float* __restrict__ wh, const float* __restrict__ wx,
    _Float16* __restrict__ whp_hi, _Float16* __restrict__ whp_lo,
    _Float16* __restrict__ wxp_hi, _Float16* __restrict__ wxp_lo)
{
    int idx = blockIdx.x * 256 + threadIdx.x;   // 0..262143
    {
        int j  = idx & 7;
        int l  = (idx >> 3) & 63;
        int nt = (idx >> 9) & 3;
        int kb = (idx >> 11) & 15;
        int w  = idx >> 15;                     // 0..7
        int k  = kb * 32 + (l >> 4) * 8 + j;
        int n  = w * 64 + nt * 16 + (l & 15);
        float v = wh[k * NHD + n];
        _Float16 hi = (_Float16)v;
        whp_hi[idx] = hi;
        whp_lo[idx] = (_Float16)(v - (float)hi);
    }
    if (idx < 65536) {
        int j  = idx & 7;
        int l  = (idx >> 3) & 63;
        int nt = (idx >> 9) & 3;
        int kb = (idx >> 11) & 3;
        int w  = idx >> 13;                     // 0..7
        int k  = kb * 32 + (l >> 4) * 8 + j;
        int n  = w * 64 + nt * 16 + (l & 15);
        float v = wx[k * NHD + n];
        _Float16 hi = (_Float16)v;
        wxp_hi[idx] = hi;
        wxp_lo[idx] = (_Float16)(v - (float)hi);
    }
}

// branch-free tanh: clamp +-9, (e-1)/(e+1), e = 2^(2x*log2e)
__device__ __forceinline__ float fast_tanh(float v) {
    float xc = fminf(fmaxf(v, -9.0f), 9.0f);
    float e  = __builtin_amdgcn_exp2f(xc * 2.8853900817779268f);
    return (e - 1.0f) * __builtin_amdgcn_rcpf(e + 1.0f);
}

#define MFMA6(AH, AL, BH0, BH1, BL0, BL1)                                          \
    acc[0] = __builtin_amdgcn_mfma_f32_16x16x32_f16((AH), (BH0), acc[0], 0, 0, 0); \
    acc[0] = __builtin_amdgcn_mfma_f32_16x16x32_f16((AL), (BH0), acc[0], 0, 0, 0); \
    acc[0] = __builtin_amdgcn_mfma_f32_16x16x32_f16((AH), (BL0), acc[0], 0, 0, 0); \
    acc[1] = __builtin_amdgcn_mfma_f32_16x16x32_f16((AH), (BH1), acc[1], 0, 0, 0); \
    acc[1] = __builtin_amdgcn_mfma_f32_16x16x32_f16((AL), (BH1), acc[1], 0, 0, 0); \
    acc[1] = __builtin_amdgcn_mfma_f32_16x16x32_f16((AH), (BL1), acc[1], 0, 0, 0);

// ---- main fused recurrence ----
__global__ __launch_bounds__(THREADS, 4) void rnn_mfma(
    const float* __restrict__ x,
    const float* __restrict__ bias,
    const _Float16* __restrict__ whp_hi, const _Float16* __restrict__ whp_lo,
    const _Float16* __restrict__ wxp_hi, const _Float16* __restrict__ wxp_lo,
    float* __restrict__ out)
{
    // fragment-linear LDS: [kb][lane][j] halfs, 16B/lane contiguous per kb.
    __shared__ _Float16 s_fh[16 * 64 * 8];     // h hi, 16 KB
    __shared__ _Float16 s_fl[16 * 64 * 8];     // h lo, 16 KB
    __shared__ _Float16 s_xh[4 * 64 * 8];      // x hi,  4 KB
    __shared__ _Float16 s_xl[4 * 64 * 8];      // x lo,  4 KB
    // LDS-resident wx_hi frags: [wave][f(7)][lane][8], f = kb*2+nt (f<7) -> 112 KB
    __shared__ _Float16 s_w[16 * 7 * 64 * 8];  // total 152 KB

    const int tid  = (int)threadIdx.x;
    const int lane = tid & 63;
    const int w    = tid >> 6;        // wave 0..15, owns cols [w*32, w*32+32)
    const int m    = lane & 15;
    const int quad = lane >> 4;
    const int row0 = (int)blockIdx.x * BR;

    // zero h fragments (h(0) = 0)
    for (int i = tid; i < 16 * 64 * 8; i += THREADS) {
        s_fh[i] = (_Float16)0.f;
        s_fl[i] = (_Float16)0.f;
    }

    // bias for this lane's 2 col-tiles
    float bv[2];
    #pragma unroll
    for (int nt = 0; nt < 2; ++nt) bv[nt] = bias[w * 32 + nt * 16 + m];

    // weight fragment base pointers (round-2 math: 32-col slice of 64-col group)
    const half8* wxh = (const half8*)wxp_hi + (size_t)(w >> 1) * 1024 + (w & 1) * 128;
    const half8* wxl = (const half8*)wxp_lo + (size_t)(w >> 1) * 1024 + (w & 1) * 128;
    const half8* whh = (const half8*)whp_hi + (size_t)(w >> 1) * 4096 + (w & 1) * 128;
    const half8* whl = (const half8*)whp_lo + (size_t)(w >> 1) * 4096 + (w & 1) * 128;

    // stage resident wx_hi frags (f = kb*2+nt, f<7) into LDS once
    #pragma unroll
    for (int f = 0; f < 7; ++f) {
        int kb = f >> 1, nt = f & 1;
        half8 v = wxh[kb * 256 + nt * 64 + lane];
        *(half8*)&s_w[((w * 7 + f) * 64 + lane) * 8] = v;
    }

    // x staging: 256 threads each own one full A-fragment lane-slice (16B):
    // frag (xkb = i>>6, lane' = i&63) holds x[row0 + (lane'&15)][xkb*32 + (lane'>>4)*8 + j]
    const int xi    = tid & 255;
    const int xkb   = xi >> 6;
    const int xlane = xi & 63;
    const float* xptr = x + (size_t)(row0 + (xlane & 15)) * (T_STEPS * NFD)
                          + xkb * 32 + (xlane >> 4) * 8;
    float4v pxa, pxb;
    if (tid < 256) {
        pxa = *(const float4v*)xptr;
        pxb = *(const float4v*)(xptr + 4);
    }

    // epilogue fragment coords (R4/R5/R7, proven)
    const int eBase = w * 64 * 8 + (m & 7);
    const int eQ    = quad * 4;
    const int eHiM  = 16 * (m >> 3);

    for (int t = 0; t < T_STEPS; ++t) {
        // (p) wx-leftover prefetch: 9 frags, cross barrier1 (R7-proven, no spill)
        half8 pbh31 = wxh[3 * 256 + 64 + lane];   // wx_hi kb3 nt1 (f=7)
        half8 pbl0[4], pbl1[4];
        #pragma unroll
        for (int kb = 0; kb < 4; ++kb) {
            pbl0[kb] = wxl[kb * 256 + lane];
            pbl1[kb] = wxl[kb * 256 + 64 + lane];
        }

        // (a) stage x(t): one 16B lane-frag per thread (conflict-free)
        if (tid < 256) {
            half8 vh, vl;
            float xs[8] = {pxa[0], pxa[1], pxa[2], pxa[3],
                           pxb[0], pxb[1], pxb[2], pxb[3]};
            #pragma unroll
            for (int j = 0; j < 8; ++j) {
                _Float16 hi = (_Float16)xs[j];
                vh[j] = hi;
                vl[j] = (_Float16)(xs[j] - (float)hi);
            }
            *(half8*)&s_xh[xi * 8] = vh;
            *(half8*)&s_xl[xi * 8] = vl;
        }
        __syncthreads();   // (1) x staged + h(t-1) frags (+ t=0: s_w, zeros) visible

        if (t + 1 < T_STEPS && tid < 256) {
            pxa = *(const float4v*)(xptr + (t + 1) * NFD);
            pxb = *(const float4v*)(xptr + (t + 1) * NFD + 4);
        }

        // stream pipeline prologue: issue kb0, kb1 (in flight under x-proj)
        half8 S[3][4];   // [slot][bh0,bh1,bl0,bl1] — static indices via full unroll
        S[0][0] = whh[0 * 256 + lane];  S[0][1] = whh[0 * 256 + 64 + lane];
        S[0][2] = whl[0 * 256 + lane];  S[0][3] = whl[0 * 256 + 64 + lane];
        S[1][0] = whh[1 * 256 + lane];  S[1][1] = whh[1 * 256 + 64 + lane];
        S[1][2] = whl[1 * 256 + lane];  S[1][3] = whl[1 * 256 + 64 + lane];

        float4v acc[2];
        #pragma unroll
        for (int nt = 0; nt < 2; ++nt) {
            acc[nt][0] = bv[nt]; acc[nt][1] = bv[nt];
            acc[nt][2] = bv[nt]; acc[nt][3] = bv[nt];
        }

        // (b) input projection: K = 128 -> 4 k-blocks; all operands LDS/regs
        {
            half8 ah, al;
            ah = *(const half8*)&s_xh[(0 * 64 + lane) * 8];
            al = *(const half8*)&s_xl[(0 * 64 + lane) * 8];
            MFMA6(ah, al,
                  *(const half8*)&s_w[((w * 7 + 0) * 64 + lane) * 8],
                  *(const half8*)&s_w[((w * 7 + 1) * 64 + lane) * 8], pbl0[0], pbl1[0]);
            ah = *(const half8*)&s_xh[(1 * 64 + lane) * 8];
            al = *(const half8*)&s_xl[(1 * 64 + lane) * 8];
            MFMA6(ah, al,
                  *(const half8*)&s_w[((w * 7 + 2) * 64 + lane) * 8],
                  *(const half8*)&s_w[((w * 7 + 3) * 64 + lane) * 8], pbl0[1], pbl1[1]);
            ah = *(const half8*)&s_xh[(2 * 64 + lane) * 8];
            al = *(const half8*)&s_xl[(2 * 64 + lane) * 8];
            MFMA6(ah, al,
                  *(const half8*)&s_w[((w * 7 + 4) * 64 + lane) * 8],
                  *(const half8*)&s_w[((w * 7 + 5) * 64 + lane) * 8], pbl0[2], pbl1[2]);
            ah = *(const half8*)&s_xh[(3 * 64 + lane) * 8];
            al = *(const half8*)&s_xl[(3 * 64 + lane) * 8];
            MFMA6(ah, al,
                  *(const half8*)&s_w[((w * 7 + 6) * 64 + lane) * 8],
                  pbh31, pbl0[3], pbl1[3]);
        }

        // (c) recurrence: software-pipelined stream, 2-deep in flight.
        //     iter kb: issue kb+2 into slot (kb+2)%3, then consume slot kb%3.
        #pragma unroll
        for (int kb = 0; kb < 16; ++kb) {
            if (kb + 2 < 16) {
                const int s = (kb + 2) % 3;
                S[s][0] = whh[(kb + 2) * 256 + lane];
                S[s][1] = whh[(kb + 2) * 256 + 64 + lane];
                S[s][2] = whl[(kb + 2) * 256 + lane];
                S[s][3] = whl[(kb + 2) * 256 + 64 + lane];
            }
            const int c = kb % 3;
            half8 ah = *(const half8*)&s_fh[(kb * 64 + lane) * 8];
            half8 al = *(const half8*)&s_fl[(kb * 64 + lane) * 8];
            MFMA6(ah, al, S[c][0], S[c][1], S[c][2], S[c][3]);
        }

        __syncthreads();   // (2) all h/x fragment reads for step t done

        // (d) epilogue: tanh, split, write h(t) fragments (or final output)
        if (t == T_STEPS - 1) {
            #pragma unroll
            for (int nt = 0; nt < 2; ++nt)
                #pragma unroll
                for (int r = 0; r < 4; ++r)
                    out[(size_t)(row0 + quad * 4 + r) * NHD + w * 32 + nt * 16 + m] =
                        fast_tanh(acc[nt][r]);
        } else {
            #pragma unroll
            for (int nt = 0; nt < 2; ++nt) {
                #pragma unroll
                for (int r = 0; r < 4; ++r) {
                    float v = fast_tanh(acc[nt][r]);
                    _Float16 hi = (_Float16)v;
                    int fo = eBase + (eQ + r + 16 * (nt * 2) + eHiM) * 8;
                    s_fh[fo] = hi;
                    s_fl[fo] = (_Float16)(v - (float)hi);
                }
            }
        }
    }
}

extern "C" void kernel_launch(void* const* d_in, const int* in_sizes, int n_in,
                              void* d_out, int out_size, void* d_ws, size_t ws_size,
                              hipStream_t stream) {
    const float* x    = (const float*)d_in[0];  // [B, 64, 128]
    const float* wx   = (const float*)d_in[1];  // [128, 512]
    const float* wh   = (const float*)d_in[2];  // [512, 512]
    const float* bias = (const float*)d_in[3];  // [512]
    float* out = (float*)d_out;                 // [B, 512]

    // workspace (fp16): whp_hi 512KB | whp_lo 512KB | wxp_hi 128KB | wxp_lo 128KB
    char* ws = (char*)d_ws;
    _Float16* whp_hi = (_Float16*)(ws);
    _Float16* whp_lo = (_Float16*)(ws + 524288);
    _Float16* wxp_hi = (_Float16*)(ws + 1048576);
    _Float16* wxp_lo = (_Float16*)(ws + 1048576 + 131072);

    rnn_prep<<<1024, 256, 0, stream>>>(wh, wx, whp_hi, whp_lo, wxp_hi, wxp_lo);

    const int B = in_sizes[0] / (T_STEPS * NFD);   // 4096
    rnn_mfma<<<B / BR, THREADS, 0, stream>>>(x, bias, whp_hi, whp_lo, wxp_hi, wxp_lo, out);
}